// Round 1
// baseline (851.467 us; speedup 1.0000x reference)
//
#include <hip/hip_runtime.h>

#define S_TOT 2048
#define BATCH 128
#define FEAT  256

// -------------------- workspace layout --------------------
// mean   : BATCH*FEAT float
// istd   : BATCH*FEAT float
// colsum : BATCH*FEAT int
// order  : BATCH*FEAT int
// counts : BATCH int

// Kernel 1: per-(b,f) mean and 1/(std+1e-6) over s in [0,n)
__global__ void k_stats(const float* __restrict__ x, const int* __restrict__ sep,
                        float* __restrict__ mean, float* __restrict__ istd) {
    const int b = blockIdx.x;
    const int f = threadIdx.x;
    const int n = sep[0];
    const float* p = x + (size_t)b * FEAT + f;
    float s = 0.f, ss = 0.f;
    for (int i = 0; i < n; ++i) {
        float v = p[(size_t)i * (BATCH * FEAT)];
        s += v;
        ss = fmaf(v, v, ss);
    }
    float m = s / (float)n;
    float var = (ss - (float)n * m * m) / (float)(n - 1);
    var = fmaxf(var, 0.f);
    float sd = sqrtf(var);
    mean[b * FEAT + f] = m;
    istd[b * FEAT + f] = 1.f / (sd + 1e-6f);
}

// Kernel 2: per-batch cov tile (64x64), normalize+clip on the fly (fp32),
// threshold > 0.999, count upper-triangle entries per column via atomics.
// NOTE: second centering (x_norm - mean(x_norm)) skipped: exactly 0 in exact
// arithmetic when clip never fires; perturbs cov by ~1e-16 vs 1e-3 margins.
__global__ void k_cov(const float* __restrict__ x, const int* __restrict__ sep,
                      const float* __restrict__ mean, const float* __restrict__ istd,
                      int* __restrict__ colsum) {
    const int tiI = blockIdx.x;   // 0..3
    const int tjJ = blockIdx.y;   // 0..3
    if (tiI > tjJ) return;        // upper-triangle tile pairs only
    const int b = blockIdx.z;
    const int ti = tiI * 64, tj = tjJ * 64;
    const int n = sep[0];
    const int t = threadIdx.x;

    __shared__ float As[32][64];
    __shared__ float Bs[32][64];

    const int c  = t & 63;    // staging column within tile
    const int kr = t >> 6;    // staging row group 0..3
    const float mA = mean[b * FEAT + ti + c], sA = istd[b * FEAT + ti + c];
    const float mB = mean[b * FEAT + tj + c], sB = istd[b * FEAT + tj + c];

    const int il = (t & 15) * 4;   // local i of this thread's 4x4 micro-tile
    const int jl = (t >> 4) * 4;   // local j

    float acc[4][4] = {};

    for (int k0 = 0; k0 < n; k0 += 32) {
#pragma unroll
        for (int r = 0; r < 8; ++r) {
            int kk = r * 4 + kr;
            int s = k0 + kk;
            float va = 0.f, vb = 0.f;
            if (s < n) {
                size_t base = (size_t)s * (BATCH * FEAT) + (size_t)b * FEAT;
                va = (x[base + ti + c] - mA) * sA;
                vb = (x[base + tj + c] - mB) * sB;
                va = fminf(fmaxf(va, -100.f), 100.f);
                vb = fminf(fmaxf(vb, -100.f), 100.f);
            }
            As[kk][c] = va;
            Bs[kk][c] = vb;
        }
        __syncthreads();
#pragma unroll 8
        for (int kk = 0; kk < 32; ++kk) {
            float4 av = *(const float4*)&As[kk][il];
            float4 bv = *(const float4*)&Bs[kk][jl];
            float a[4] = {av.x, av.y, av.z, av.w};
            float bb[4] = {bv.x, bv.y, bv.z, bv.w};
#pragma unroll
            for (int i = 0; i < 4; ++i)
#pragma unroll
                for (int j = 0; j < 4; ++j)
                    acc[i][j] = fmaf(a[i], bb[j], acc[i][j]);
        }
        __syncthreads();
    }

    const float denom = 1.f / (float)(n - 1);
    int cnt[4] = {0, 0, 0, 0};
#pragma unroll
    for (int i = 0; i < 4; ++i) {
#pragma unroll
        for (int j = 0; j < 4; ++j) {
            int gi = ti + il + i;
            int gj = tj + jl + j;
            float cv = acc[i][j] * denom;
            if (gi <= gj && cv > 0.999f) cnt[j]++;
        }
    }
#pragma unroll
    for (int j = 0; j < 4; ++j)
        if (cnt[j]) atomicAdd(&colsum[b * FEAT + tj + jl + j], cnt[j]);
}

// Kernel 3: stable order (selected features first) + counts, ballot prefix.
__global__ void k_select(const int* __restrict__ colsum, int* __restrict__ order,
                         int* __restrict__ counts) {
    __shared__ int wsum[4];
    const int b = blockIdx.x;
    const int j = threadIdx.x;         // 0..255
    const int sel = (colsum[b * FEAT + j] == 1) ? 1 : 0;
    unsigned long long mask = __ballot(sel);
    const int lane = j & 63;
    const int wid = j >> 6;
    int pre = __popcll(mask & ((1ull << lane) - 1ull));
    if (lane == 0) wsum[wid] = __popcll(mask);
    __syncthreads();
    int woff = 0;
#pragma unroll
    for (int w = 0; w < 4; ++w) woff += (w < wid) ? wsum[w] : 0;
    const int total = wsum[0] + wsum[1] + wsum[2] + wsum[3];
    if (sel) {
        order[b * FEAT + woff + pre] = j;
    } else {
        int unsel_pre = j - (woff + pre);   // unselected before j
        order[b * FEAT + total + unsel_pre] = j;
    }
    if (j == 0) counts[b] = total;
}

// Kernel 4: out[s,b,k] = k < counts[b] ? x[s,b,order[b,k]] : 0
__global__ void k_gather(const float* __restrict__ x, const int* __restrict__ order,
                         const int* __restrict__ counts, float* __restrict__ out) {
    const int b = blockIdx.y;
    const int s = blockIdx.x * 4 + (threadIdx.x >> 6);
    const int k4 = (threadIdx.x & 63) * 4;
    const int4 ord = *(const int4*)&order[b * FEAT + k4];
    const int cnt = counts[b];
    const size_t base = (size_t)s * (BATCH * FEAT) + (size_t)b * FEAT;
    float4 v;
    v.x = (k4 + 0 < cnt) ? x[base + ord.x] : 0.f;
    v.y = (k4 + 1 < cnt) ? x[base + ord.y] : 0.f;
    v.z = (k4 + 2 < cnt) ? x[base + ord.z] : 0.f;
    v.w = (k4 + 3 < cnt) ? x[base + ord.w] : 0.f;
    *(float4*)&out[base + k4] = v;
}

extern "C" void kernel_launch(void* const* d_in, const int* in_sizes, int n_in,
                              void* d_out, int out_size, void* d_ws, size_t ws_size,
                              hipStream_t stream) {
    const float* x = (const float*)d_in[0];
    const int* sep = (const int*)d_in[1];
    float* out = (float*)d_out;

    float* mean = (float*)d_ws;
    float* istd = mean + BATCH * FEAT;
    int* colsum = (int*)(istd + BATCH * FEAT);
    int* order = colsum + BATCH * FEAT;
    int* counts = order + BATCH * FEAT;

    k_stats<<<dim3(BATCH), dim3(FEAT), 0, stream>>>(x, sep, mean, istd);

    hipMemsetAsync(colsum, 0, BATCH * FEAT * sizeof(int), stream);

    k_cov<<<dim3(4, 4, BATCH), dim3(256), 0, stream>>>(x, sep, mean, istd, colsum);

    k_select<<<dim3(BATCH), dim3(FEAT), 0, stream>>>(colsum, order, counts);

    k_gather<<<dim3(S_TOT / 4, BATCH), dim3(256), 0, stream>>>(x, order, counts, out);
}

// Round 2
// 471.932 us; speedup vs baseline: 1.8042x; 1.8042x over previous
//
#include <hip/hip_runtime.h>

#define S_TOT 2048
#define BATCH 128
#define FEAT  256
#define CHUNKS 8

// -------------------- workspace layout --------------------
// mean   : BATCH*FEAT float
// istd   : BATCH*FEAT float
// colsum : BATCH*FEAT int
// order  : BATCH*FEAT int
// counts : BATCH int
// part   : BATCH*CHUNKS*2*FEAT float   (partial sum / sumsq)

// Kernel 1a: partial sums over an s-chunk. grid (BATCH, CHUNKS), block 256.
// Thread t handles features (t&63)*4..+3 (float4), s-rows t>>6 (mod 4).
__global__ void k_stats1(const float* __restrict__ x, const int* __restrict__ sep,
                         float* __restrict__ part) {
    const int b = blockIdx.x;
    const int ch = blockIdx.y;
    const int n = sep[0];
    const int rpc = (n + CHUNKS - 1) / CHUNKS;
    const int s0 = ch * rpc;
    const int s1 = min(n, s0 + rpc);
    const int t = threadIdx.x;
    const int f4 = (t & 63) * 4;
    const int sr = t >> 6;

    float4 sum = {0.f, 0.f, 0.f, 0.f};
    float4 ssq = {0.f, 0.f, 0.f, 0.f};
    for (int s = s0 + sr; s < s1; s += 4) {
        float4 v = *(const float4*)&x[(size_t)s * (BATCH * FEAT) + b * FEAT + f4];
        sum.x += v.x; sum.y += v.y; sum.z += v.z; sum.w += v.w;
        ssq.x = fmaf(v.x, v.x, ssq.x);
        ssq.y = fmaf(v.y, v.y, ssq.y);
        ssq.z = fmaf(v.z, v.z, ssq.z);
        ssq.w = fmaf(v.w, v.w, ssq.w);
    }

    __shared__ float4 ls[2][256];
    ls[0][t] = sum;
    ls[1][t] = ssq;
    __syncthreads();
    if (t < 64) {
#pragma unroll
        for (int r = 1; r < 4; ++r) {
            float4 a = ls[0][t + 64 * r];
            sum.x += a.x; sum.y += a.y; sum.z += a.z; sum.w += a.w;
            float4 q = ls[1][t + 64 * r];
            ssq.x += q.x; ssq.y += q.y; ssq.z += q.z; ssq.w += q.w;
        }
        float* dst = &part[(size_t)(b * CHUNKS + ch) * 2 * FEAT];
        *(float4*)&dst[f4] = sum;
        *(float4*)&dst[FEAT + f4] = ssq;
    }
}

// Kernel 1b: fold CHUNKS partials -> mean, 1/(std+1e-6). grid BATCH, block FEAT.
__global__ void k_stats2(const float* __restrict__ part, const int* __restrict__ sep,
                         float* __restrict__ mean, float* __restrict__ istd) {
    const int b = blockIdx.x;
    const int f = threadIdx.x;
    const int n = sep[0];
    float s = 0.f, ss = 0.f;
#pragma unroll
    for (int c = 0; c < CHUNKS; ++c) {
        const float* p = &part[(size_t)(b * CHUNKS + c) * 2 * FEAT];
        s += p[f];
        ss += p[FEAT + f];
    }
    float m = s / (float)n;
    float var = (ss - (float)n * m * m) / (float)(n - 1);
    var = fmaxf(var, 0.f);
    float sd = sqrtf(var);
    mean[b * FEAT + f] = m;
    istd[b * FEAT + f] = 1.f / (sd + 1e-6f);
}

// Kernel 2: per-batch cov tile (64x64), normalize+clip on the fly (fp32),
// threshold > 0.999, count upper-triangle entries per column via atomics.
// NOTE: second centering (x_norm - mean(x_norm)) skipped: exactly 0 in exact
// arithmetic when clip never fires; perturbs cov by ~1e-16 vs 1e-3 margins.
__global__ void k_cov(const float* __restrict__ x, const int* __restrict__ sep,
                      const float* __restrict__ mean, const float* __restrict__ istd,
                      int* __restrict__ colsum) {
    const int tiI = blockIdx.x;   // 0..3
    const int tjJ = blockIdx.y;   // 0..3
    if (tiI > tjJ) return;        // upper-triangle tile pairs only
    const int b = blockIdx.z;
    const int ti = tiI * 64, tj = tjJ * 64;
    const int n = sep[0];
    const int t = threadIdx.x;

    __shared__ float As[32][64];
    __shared__ float Bs[32][64];

    const int c  = t & 63;    // staging column within tile
    const int kr = t >> 6;    // staging row group 0..3
    const float mA = mean[b * FEAT + ti + c], sA = istd[b * FEAT + ti + c];
    const float mB = mean[b * FEAT + tj + c], sB = istd[b * FEAT + tj + c];

    const int il = (t & 15) * 4;   // local i of this thread's 4x4 micro-tile
    const int jl = (t >> 4) * 4;   // local j

    float acc[4][4] = {};

    for (int k0 = 0; k0 < n; k0 += 32) {
#pragma unroll
        for (int r = 0; r < 8; ++r) {
            int kk = r * 4 + kr;
            int s = k0 + kk;
            float va = 0.f, vb = 0.f;
            if (s < n) {
                size_t base = (size_t)s * (BATCH * FEAT) + (size_t)b * FEAT;
                va = (x[base + ti + c] - mA) * sA;
                vb = (x[base + tj + c] - mB) * sB;
                va = fminf(fmaxf(va, -100.f), 100.f);
                vb = fminf(fmaxf(vb, -100.f), 100.f);
            }
            As[kk][c] = va;
            Bs[kk][c] = vb;
        }
        __syncthreads();
#pragma unroll 8
        for (int kk = 0; kk < 32; ++kk) {
            float4 av = *(const float4*)&As[kk][il];
            float4 bv = *(const float4*)&Bs[kk][jl];
            float a[4] = {av.x, av.y, av.z, av.w};
            float bb[4] = {bv.x, bv.y, bv.z, bv.w};
#pragma unroll
            for (int i = 0; i < 4; ++i)
#pragma unroll
                for (int j = 0; j < 4; ++j)
                    acc[i][j] = fmaf(a[i], bb[j], acc[i][j]);
        }
        __syncthreads();
    }

    const float denom = 1.f / (float)(n - 1);
    int cnt[4] = {0, 0, 0, 0};
#pragma unroll
    for (int i = 0; i < 4; ++i) {
#pragma unroll
        for (int j = 0; j < 4; ++j) {
            int gi = ti + il + i;
            int gj = tj + jl + j;
            float cv = acc[i][j] * denom;
            if (gi <= gj && cv > 0.999f) cnt[j]++;
        }
    }
#pragma unroll
    for (int j = 0; j < 4; ++j)
        if (cnt[j]) atomicAdd(&colsum[b * FEAT + tj + jl + j], cnt[j]);
}

// Kernel 3: stable order (selected features first) + counts, ballot prefix.
__global__ void k_select(const int* __restrict__ colsum, int* __restrict__ order,
                         int* __restrict__ counts) {
    __shared__ int wsum[4];
    const int b = blockIdx.x;
    const int j = threadIdx.x;         // 0..255
    const int sel = (colsum[b * FEAT + j] == 1) ? 1 : 0;
    unsigned long long mask = __ballot(sel);
    const int lane = j & 63;
    const int wid = j >> 6;
    int pre = __popcll(mask & ((1ull << lane) - 1ull));
    if (lane == 0) wsum[wid] = __popcll(mask);
    __syncthreads();
    int woff = 0;
#pragma unroll
    for (int w = 0; w < 4; ++w) woff += (w < wid) ? wsum[w] : 0;
    const int total = wsum[0] + wsum[1] + wsum[2] + wsum[3];
    if (sel) {
        order[b * FEAT + woff + pre] = j;
    } else {
        int unsel_pre = j - (woff + pre);   // unselected before j
        order[b * FEAT + total + unsel_pre] = j;
    }
    if (j == 0) counts[b] = total;
}

// Kernel 4: out[s,b,k] = k < counts[b] ? x[s,b,order[b,k]] : 0
__global__ void k_gather(const float* __restrict__ x, const int* __restrict__ order,
                         const int* __restrict__ counts, float* __restrict__ out) {
    const int b = blockIdx.y;
    const int s = blockIdx.x * 4 + (threadIdx.x >> 6);
    const int k4 = (threadIdx.x & 63) * 4;
    const int4 ord = *(const int4*)&order[b * FEAT + k4];
    const int cnt = counts[b];
    const size_t base = (size_t)s * (BATCH * FEAT) + (size_t)b * FEAT;
    float4 v;
    v.x = (k4 + 0 < cnt) ? x[base + ord.x] : 0.f;
    v.y = (k4 + 1 < cnt) ? x[base + ord.y] : 0.f;
    v.z = (k4 + 2 < cnt) ? x[base + ord.z] : 0.f;
    v.w = (k4 + 3 < cnt) ? x[base + ord.w] : 0.f;
    *(float4*)&out[base + k4] = v;
}

extern "C" void kernel_launch(void* const* d_in, const int* in_sizes, int n_in,
                              void* d_out, int out_size, void* d_ws, size_t ws_size,
                              hipStream_t stream) {
    const float* x = (const float*)d_in[0];
    const int* sep = (const int*)d_in[1];
    float* out = (float*)d_out;

    float* mean = (float*)d_ws;
    float* istd = mean + BATCH * FEAT;
    int* colsum = (int*)(istd + BATCH * FEAT);
    int* order = colsum + BATCH * FEAT;
    int* counts = order + BATCH * FEAT;
    float* part = (float*)(counts + BATCH);   // BATCH*CHUNKS*2*FEAT floats

    k_stats1<<<dim3(BATCH, CHUNKS), dim3(256), 0, stream>>>(x, sep, part);
    k_stats2<<<dim3(BATCH), dim3(FEAT), 0, stream>>>(part, sep, mean, istd);

    hipMemsetAsync(colsum, 0, BATCH * FEAT * sizeof(int), stream);

    k_cov<<<dim3(4, 4, BATCH), dim3(256), 0, stream>>>(x, sep, mean, istd, colsum);

    k_select<<<dim3(BATCH), dim3(FEAT), 0, stream>>>(colsum, order, counts);

    k_gather<<<dim3(S_TOT / 4, BATCH), dim3(256), 0, stream>>>(x, order, counts, out);
}

// Round 3
// 291.078 us; speedup vs baseline: 2.9252x; 1.6213x over previous
//
#include <hip/hip_runtime.h>

#define S_TOT 2048
#define BATCH 128
#define FEAT  256
#define CHUNKS 8
#define ROWH 36   // padded LDS row length in halves (72 B -> conflict-free-ish)

typedef _Float16 f16x4 __attribute__((ext_vector_type(4)));
typedef _Float16 f16x2 __attribute__((ext_vector_type(2)));
typedef float f32x4 __attribute__((ext_vector_type(4)));

// Kernel 1a: partial sums over an s-chunk. grid (BATCH, CHUNKS), block 256.
__global__ void k_stats1(const float* __restrict__ x, const int* __restrict__ sep,
                         float* __restrict__ part) {
    const int b = blockIdx.x;
    const int ch = blockIdx.y;
    const int n = sep[0];
    const int rpc = (n + CHUNKS - 1) / CHUNKS;
    const int s0 = ch * rpc;
    const int s1 = min(n, s0 + rpc);
    const int t = threadIdx.x;
    const int f4 = (t & 63) * 4;
    const int sr = t >> 6;

    float4 sum = {0.f, 0.f, 0.f, 0.f};
    float4 ssq = {0.f, 0.f, 0.f, 0.f};
    for (int s = s0 + sr; s < s1; s += 4) {
        float4 v = *(const float4*)&x[(size_t)s * (BATCH * FEAT) + b * FEAT + f4];
        sum.x += v.x; sum.y += v.y; sum.z += v.z; sum.w += v.w;
        ssq.x = fmaf(v.x, v.x, ssq.x);
        ssq.y = fmaf(v.y, v.y, ssq.y);
        ssq.z = fmaf(v.z, v.z, ssq.z);
        ssq.w = fmaf(v.w, v.w, ssq.w);
    }

    __shared__ float4 ls[2][256];
    ls[0][t] = sum;
    ls[1][t] = ssq;
    __syncthreads();
    if (t < 64) {
#pragma unroll
        for (int r = 1; r < 4; ++r) {
            float4 a = ls[0][t + 64 * r];
            sum.x += a.x; sum.y += a.y; sum.z += a.z; sum.w += a.w;
            float4 q = ls[1][t + 64 * r];
            ssq.x += q.x; ssq.y += q.y; ssq.z += q.z; ssq.w += q.w;
        }
        float* dst = &part[(size_t)(b * CHUNKS + ch) * 2 * FEAT];
        *(float4*)&dst[f4] = sum;
        *(float4*)&dst[FEAT + f4] = ssq;
    }
}

// Kernel 1b: fold partials -> mean, 1/(std+1e-6).
__global__ void k_stats2(const float* __restrict__ part, const int* __restrict__ sep,
                         float* __restrict__ mean, float* __restrict__ istd) {
    const int b = blockIdx.x;
    const int f = threadIdx.x;
    const int n = sep[0];
    float s = 0.f, ss = 0.f;
#pragma unroll
    for (int c = 0; c < CHUNKS; ++c) {
        const float* p = &part[(size_t)(b * CHUNKS + c) * 2 * FEAT];
        s += p[f];
        ss += p[FEAT + f];
    }
    float m = s / (float)n;
    float var = (ss - (float)n * m * m) / (float)(n - 1);
    var = fmaxf(var, 0.f);
    float sd = sqrtf(var);
    mean[b * FEAT + f] = m;
    istd[b * FEAT + f] = 1.f / (sd + 1e-6f);
}

// Kernel 2 (MFMA): one block per batch, full 256x256 Gram of normalized f16
// values, fp32 accumulation via v_mfma_f32_16x16x16_f16. LDS tile T[feat][k]
// (k-chunk 32, padded row) serves both A (rows m) and B (rows n) fragments:
// frag = 4 consecutive k at fixed feature row -> one ds_read_b64.
// Second centering (x_norm - mean(x_norm)) skipped: ~1e-16 vs 1e-3 margins.
__global__ __launch_bounds__(1024) void k_cov(
        const float* __restrict__ x, const int* __restrict__ sep,
        const float* __restrict__ mean, const float* __restrict__ istd,
        int* __restrict__ colsum) {
    const int b = blockIdx.x;
    const int n = sep[0];
    const int t = threadIdx.x;
    const int l = t & 63;
    const int w = t >> 6;           // 0..15
    const int wm = w >> 2, wn = w & 3;
    const int l15 = l & 15, lg = l >> 4;

    __shared__ _Float16 T[FEAT][ROWH];

    // staging role: thread covers feature f, k-slots kh*8 .. kh*8+7
    const int f = t & 255;
    const int kh = t >> 8;          // 0..3
    const float mF = mean[b * FEAT + f];
    const float sF = istd[b * FEAT + f];

    f32x4 acc[4][4];
#pragma unroll
    for (int r = 0; r < 4; ++r)
#pragma unroll
        for (int c = 0; c < 4; ++c)
            acc[r][c] = (f32x4){0.f, 0.f, 0.f, 0.f};

    const size_t xoff = (size_t)b * FEAT + f;
    for (int k0 = 0; k0 < n; k0 += 32) {
#pragma unroll
        for (int i = 0; i < 8; i += 2) {
            const int kk = kh * 8 + i;
            const int s0 = k0 + kk, s1 = s0 + 1;
            float v0 = (s0 < n) ? x[(size_t)s0 * (BATCH * FEAT) + xoff] : 0.f;
            float v1 = (s1 < n) ? x[(size_t)s1 * (BATCH * FEAT) + xoff] : 0.f;
            v0 = fminf(fmaxf((v0 - mF) * sF, -100.f), 100.f);
            v1 = fminf(fmaxf((v1 - mF) * sF, -100.f), 100.f);
            f16x2 h = {(_Float16)v0, (_Float16)v1};
            *(f16x2*)&T[f][kk] = h;
        }
        __syncthreads();
#pragma unroll
        for (int ks = 0; ks < 2; ++ks) {
            const int kloc = ks * 16 + 4 * lg;
            f16x4 a[4], bb[4];
#pragma unroll
            for (int r = 0; r < 4; ++r)
                a[r] = *(const f16x4*)&T[(wm * 4 + r) * 16 + l15][kloc];
#pragma unroll
            for (int c = 0; c < 4; ++c)
                bb[c] = *(const f16x4*)&T[(wn * 4 + c) * 16 + l15][kloc];
#pragma unroll
            for (int r = 0; r < 4; ++r)
#pragma unroll
                for (int c = 0; c < 4; ++c)
                    acc[r][c] = __builtin_amdgcn_mfma_f32_16x16x16f16(
                        a[r], bb[c], acc[r][c], 0, 0, 0);
        }
        __syncthreads();
    }

    const float denom = 1.f / (float)(n - 1);
#pragma unroll
    for (int c = 0; c < 4; ++c) {
        const int gj = (wn * 4 + c) * 16 + l15;
        int cnt = 0;
#pragma unroll
        for (int r = 0; r < 4; ++r) {
            const int gib = (wm * 4 + r) * 16 + 4 * lg;
#pragma unroll
            for (int q = 0; q < 4; ++q) {
                float cv = acc[r][c][q] * denom;
                if (gib + q <= gj && cv > 0.999f) cnt++;
            }
        }
        if (cnt) atomicAdd(&colsum[b * FEAT + gj], cnt);
    }
}

// Kernel 3: stable order (selected features first) + counts, ballot prefix.
__global__ void k_select(const int* __restrict__ colsum, int* __restrict__ order,
                         int* __restrict__ counts) {
    __shared__ int wsum[4];
    const int b = blockIdx.x;
    const int j = threadIdx.x;         // 0..255
    const int sel = (colsum[b * FEAT + j] == 1) ? 1 : 0;
    unsigned long long mask = __ballot(sel);
    const int lane = j & 63;
    const int wid = j >> 6;
    int pre = __popcll(mask & ((1ull << lane) - 1ull));
    if (lane == 0) wsum[wid] = __popcll(mask);
    __syncthreads();
    int woff = 0;
#pragma unroll
    for (int w = 0; w < 4; ++w) woff += (w < wid) ? wsum[w] : 0;
    const int total = wsum[0] + wsum[1] + wsum[2] + wsum[3];
    if (sel) {
        order[b * FEAT + woff + pre] = j;
    } else {
        int unsel_pre = j - (woff + pre);
        order[b * FEAT + total + unsel_pre] = j;
    }
    if (j == 0) counts[b] = total;
}

// Kernel 4: out[s,b,k] = k < counts[b] ? x[s,b,order[b,k]] : 0
__global__ void k_gather(const float* __restrict__ x, const int* __restrict__ order,
                         const int* __restrict__ counts, float* __restrict__ out) {
    const int b = blockIdx.y;
    const int s = blockIdx.x * 4 + (threadIdx.x >> 6);
    const int k4 = (threadIdx.x & 63) * 4;
    const int4 ord = *(const int4*)&order[b * FEAT + k4];
    const int cnt = counts[b];
    const size_t base = (size_t)s * (BATCH * FEAT) + (size_t)b * FEAT;
    float4 v;
    v.x = (k4 + 0 < cnt) ? x[base + ord.x] : 0.f;
    v.y = (k4 + 1 < cnt) ? x[base + ord.y] : 0.f;
    v.z = (k4 + 2 < cnt) ? x[base + ord.z] : 0.f;
    v.w = (k4 + 3 < cnt) ? x[base + ord.w] : 0.f;
    *(float4*)&out[base + k4] = v;
}

extern "C" void kernel_launch(void* const* d_in, const int* in_sizes, int n_in,
                              void* d_out, int out_size, void* d_ws, size_t ws_size,
                              hipStream_t stream) {
    const float* x = (const float*)d_in[0];
    const int* sep = (const int*)d_in[1];
    float* out = (float*)d_out;

    float* mean = (float*)d_ws;
    float* istd = mean + BATCH * FEAT;
    int* colsum = (int*)(istd + BATCH * FEAT);
    int* order = colsum + BATCH * FEAT;
    int* counts = order + BATCH * FEAT;
    float* part = (float*)(counts + BATCH);   // BATCH*CHUNKS*2*FEAT floats

    k_stats1<<<dim3(BATCH, CHUNKS), dim3(256), 0, stream>>>(x, sep, part);
    k_stats2<<<dim3(BATCH), dim3(FEAT), 0, stream>>>(part, sep, mean, istd);

    hipMemsetAsync(colsum, 0, BATCH * FEAT * sizeof(int), stream);

    k_cov<<<dim3(BATCH), dim3(1024), 0, stream>>>(x, sep, mean, istd, colsum);

    k_select<<<dim3(BATCH), dim3(FEAT), 0, stream>>>(colsum, order, counts);

    k_gather<<<dim3(S_TOT / 4, BATCH), dim3(256), 0, stream>>>(x, order, counts, out);
}

// Round 4
// 281.862 us; speedup vs baseline: 3.0209x; 1.0327x over previous
//
#include <hip/hip_runtime.h>

#define S_TOT 2048
#define BATCH 128
#define FEAT  256
#define ROWH  36    // padded LDS row length in halves (72 B, 8B-aligned rows)
#define GROWS 16    // rows per gather block

typedef _Float16 f16x4 __attribute__((ext_vector_type(4)));
typedef _Float16 f16x2 __attribute__((ext_vector_type(2)));
typedef float f32x4 __attribute__((ext_vector_type(4)));

// Kernel 1 (fused stats + Gram via MFMA): one block per batch.
// Correlation is affine-invariant, so we stage RAW f16 values, MFMA the
// 256x256 Gram G = sum_k h_i h_k, accumulate per-feature sum/sumsq of the
// SAME f16-rounded values in fp32 (so the diagonal cancels to 1.0 exactly
// up to MFMA-vs-VALU summation order, ~1e-6), then threshold
//   (G - n*mi*mj) / ((n-1)*si*sj) > 0.999
// Ref's +1e-6 std shift scales cov by ~(1-2e-6): irrelevant vs 1e-3 margins.
// sigma=0 features: is_=0 -> cv=0 -> never selected (matches ref).
__global__ __launch_bounds__(1024) void k_cov(
        const float* __restrict__ x, const int* __restrict__ sep,
        int* __restrict__ colsum) {
    const int b = blockIdx.x;
    const int n = sep[0];
    const int t = threadIdx.x;
    const int l = t & 63;
    const int w = t >> 6;           // 0..15
    const int wm = w >> 2, wn = w & 3;
    const int l15 = l & 15, lg = l >> 4;

    __shared__ _Float16 T[FEAT][ROWH];
    __shared__ float red[2][4][FEAT];
    __shared__ float ms[FEAT], is_[FEAT];

    // staging role: thread covers feature f, k-slots kh*8 .. kh*8+7
    const int f = t & 255;
    const int kh = t >> 8;          // 0..3

    f32x4 acc[4][4];
#pragma unroll
    for (int r = 0; r < 4; ++r)
#pragma unroll
        for (int c = 0; c < 4; ++c)
            acc[r][c] = (f32x4){0.f, 0.f, 0.f, 0.f};

    float psum = 0.f, psq = 0.f;

    const size_t xoff = (size_t)b * FEAT + f;
    for (int k0 = 0; k0 < n; k0 += 32) {
#pragma unroll
        for (int i = 0; i < 8; i += 2) {
            const int kk = kh * 8 + i;
            const int s0 = k0 + kk, s1 = s0 + 1;
            float v0 = (s0 < n) ? x[(size_t)s0 * (BATCH * FEAT) + xoff] : 0.f;
            float v1 = (s1 < n) ? x[(size_t)s1 * (BATCH * FEAT) + xoff] : 0.f;
            _Float16 h0 = (_Float16)v0, h1 = (_Float16)v1;
            float r0 = (float)h0, r1 = (float)h1;
            psum += r0 + r1;
            psq = fmaf(r0, r0, psq);
            psq = fmaf(r1, r1, psq);
            *(f16x2*)&T[f][kk] = (f16x2){h0, h1};
        }
        __syncthreads();
#pragma unroll
        for (int ks = 0; ks < 2; ++ks) {
            const int kloc = ks * 16 + 4 * lg;
            f16x4 a[4], bb[4];
#pragma unroll
            for (int r = 0; r < 4; ++r)
                a[r] = *(const f16x4*)&T[(wm * 4 + r) * 16 + l15][kloc];
#pragma unroll
            for (int c = 0; c < 4; ++c)
                bb[c] = *(const f16x4*)&T[(wn * 4 + c) * 16 + l15][kloc];
#pragma unroll
            for (int r = 0; r < 4; ++r)
#pragma unroll
                for (int c = 0; c < 4; ++c)
                    acc[r][c] = __builtin_amdgcn_mfma_f32_16x16x16f16(
                        a[r], bb[c], acc[r][c], 0, 0, 0);
        }
        __syncthreads();
    }

    // fold per-feature partial sums (4 kh-threads per feature)
    red[0][kh][f] = psum;
    red[1][kh][f] = psq;
    __syncthreads();
    if (t < FEAT) {
        float s = red[0][0][t] + red[0][1][t] + red[0][2][t] + red[0][3][t];
        float q = red[1][0][t] + red[1][1][t] + red[1][2][t] + red[1][3][t];
        float m = s / (float)n;
        float var = (q - (float)n * m * m) / (float)(n - 1);
        ms[t] = m;
        is_[t] = (var > 0.f) ? rsqrtf(var) : 0.f;
    }
    __syncthreads();

    const float fn = (float)n;
    const float inv_nm1 = 1.f / (float)(n - 1);
#pragma unroll
    for (int c = 0; c < 4; ++c) {
        const int gj = (wn * 4 + c) * 16 + l15;
        const float mj = ms[gj], ij = is_[gj];
        int cnt = 0;
#pragma unroll
        for (int r = 0; r < 4; ++r) {
            const int gib = (wm * 4 + r) * 16 + 4 * lg;
#pragma unroll
            for (int q = 0; q < 4; ++q) {
                const int gi = gib + q;
                float cv = (acc[r][c][q] - fn * ms[gi] * mj) * inv_nm1 * is_[gi] * ij;
                if (gi <= gj && cv > 0.999f) cnt++;
            }
        }
        if (cnt) atomicAdd(&colsum[b * FEAT + gj], cnt);
    }
}

// Kernel 2: stable order (selected features first) + counts, ballot prefix.
__global__ void k_select(const int* __restrict__ colsum, int* __restrict__ order,
                         int* __restrict__ counts) {
    __shared__ int wsum[4];
    const int b = blockIdx.x;
    const int j = threadIdx.x;         // 0..255
    const int sel = (colsum[b * FEAT + j] == 1) ? 1 : 0;
    unsigned long long mask = __ballot(sel);
    const int lane = j & 63;
    const int wid = j >> 6;
    int pre = __popcll(mask & ((1ull << lane) - 1ull));
    if (lane == 0) wsum[wid] = __popcll(mask);
    __syncthreads();
    int woff = 0;
#pragma unroll
    for (int w = 0; w < 4; ++w) woff += (w < wid) ? wsum[w] : 0;
    const int total = wsum[0] + wsum[1] + wsum[2] + wsum[3];
    if (sel) {
        order[b * FEAT + woff + pre] = j;
    } else {
        int unsel_pre = j - (woff + pre);
        order[b * FEAT + total + unsel_pre] = j;
    }
    if (j == 0) counts[b] = total;
}

// Kernel 3: gather through LDS. Stage GROWS rows coalesced (float4), permute
// in LDS (thread t owns column k=t -> near-consecutive LDS addresses for
// near-identity permutations, ~2-way banks), store contiguous dwords.
__global__ __launch_bounds__(256) void k_gather(
        const float* __restrict__ x, const int* __restrict__ order,
        const int* __restrict__ counts, float* __restrict__ out) {
    const int b = blockIdx.y;
    const int s0 = blockIdx.x * GROWS;
    const int t = threadIdx.x;

    __shared__ float T[GROWS][FEAT];
    __shared__ int ord_s[FEAT];
    __shared__ int cnt_s;

    ord_s[t] = order[b * FEAT + t];
    if (t == 0) cnt_s = counts[b];

    const size_t bbase = (size_t)b * FEAT;
#pragma unroll
    for (int i = 0; i < (GROWS * FEAT) / (256 * 4); ++i) {  // 4 float4 per thread
        const int idx = i * 256 + t;
        const int row = idx >> 6;
        const int f4 = (idx & 63) * 4;
        float4 v = *(const float4*)&x[(size_t)(s0 + row) * (BATCH * FEAT) + bbase + f4];
        *(float4*)&T[row][f4] = v;
    }
    __syncthreads();

    const int o = ord_s[t];
    const bool keep = t < cnt_s;
#pragma unroll
    for (int r = 0; r < GROWS; ++r) {
        float v = T[r][o];
        out[(size_t)(s0 + r) * (BATCH * FEAT) + bbase + t] = keep ? v : 0.f;
    }
}

extern "C" void kernel_launch(void* const* d_in, const int* in_sizes, int n_in,
                              void* d_out, int out_size, void* d_ws, size_t ws_size,
                              hipStream_t stream) {
    const float* x = (const float*)d_in[0];
    const int* sep = (const int*)d_in[1];
    float* out = (float*)d_out;

    int* colsum = (int*)d_ws;
    int* order = colsum + BATCH * FEAT;
    int* counts = order + BATCH * FEAT;

    hipMemsetAsync(colsum, 0, BATCH * FEAT * sizeof(int), stream);

    k_cov<<<dim3(BATCH), dim3(1024), 0, stream>>>(x, sep, colsum);

    k_select<<<dim3(BATCH), dim3(FEAT), 0, stream>>>(colsum, order, counts);

    k_gather<<<dim3(S_TOT / GROWS, BATCH), dim3(256), 0, stream>>>(x, order, counts, out);
}

// Round 5
// 168.991 us; speedup vs baseline: 5.0385x; 1.6679x over previous
//
#include <hip/hip_runtime.h>

#define S_TOT 2048
#define BATCH 128
#define FEAT  256
#define CHUNK 64    // k-rows per pipeline stage
#define ROWH  68    // 64 halves + 4 pad; 136 B row stride -> 2-bank stagger
#define GROWS 16    // rows per gather block

typedef _Float16 f16x4 __attribute__((ext_vector_type(4)));
typedef _Float16 f16x2 __attribute__((ext_vector_type(2)));
typedef float f32x4 __attribute__((ext_vector_type(4)));

// Fused stats + Gram via MFMA, double-buffered (T14 issue-early/write-late).
// Correlation is affine-invariant: stage RAW f16 values, MFMA the 256x256
// Gram G, accumulate per-feature sum/sumsq of the SAME f16-rounded values in
// fp32, then threshold (G - n*mi*mj) / ((n-1)*si*sj) > 0.999.
// Ref's +1e-6 std shift scales cov by ~2e-6: irrelevant vs 1e-3 margins.
// sigma=0 features: is_=0 -> cv=0 -> never selected (matches ref).
// Gram is symmetric, so C vs C^T ambiguity in the MFMA C/D mapping is
// provably harmless for the upper-tri column counts.
__global__ __launch_bounds__(1024) void k_cov(
        const float* __restrict__ x, const int* __restrict__ sep,
        int* __restrict__ colsum) {
    const int b = blockIdx.x;
    const int n = sep[0];
    const int t = threadIdx.x;
    const int l = t & 63;
    const int w = t >> 6;           // 0..15 (4x4 wave grid, 64x64 out each)
    const int wm = w >> 2, wn = w & 3;
    const int l15 = l & 15, lg = l >> 4;

    __shared__ _Float16 T[2][FEAT][ROWH];
    __shared__ float red[2][4][FEAT];
    __shared__ float ms[FEAT], is_[FEAT];

    // staging role: thread covers feature f, k-slots kg*16 .. kg*16+15
    const int f = t & 255;
    const int kg = t >> 8;          // 0..3

    f32x4 acc[4][4];
#pragma unroll
    for (int r = 0; r < 4; ++r)
#pragma unroll
        for (int c = 0; c < 4; ++c)
            acc[r][c] = (f32x4){0.f, 0.f, 0.f, 0.f};

    float psum = 0.f, psq = 0.f;
    float stage[16];

    const size_t xoff = (size_t)b * FEAT + f;
    const int NC = (n + CHUNK - 1) / CHUNK;

    // prologue: chunk 0 -> regs -> buf 0
    {
        const int k0 = kg * 16;
#pragma unroll
        for (int i = 0; i < 16; ++i) {
            const int s = k0 + i;
            stage[i] = (s < n) ? x[(size_t)s * (BATCH * FEAT) + xoff] : 0.f;
        }
#pragma unroll
        for (int i = 0; i < 16; i += 2) {
            _Float16 h0 = (_Float16)stage[i], h1 = (_Float16)stage[i + 1];
            float r0 = (float)h0, r1 = (float)h1;
            psum += r0 + r1;
            psq = fmaf(r0, r0, psq);
            psq = fmaf(r1, r1, psq);
            *(f16x2*)&T[0][f][k0 + i] = (f16x2){h0, h1};
        }
    }
    __syncthreads();

    for (int c = 0; c < NC; ++c) {
        const int cur = c & 1;
        const bool more = (c + 1 < NC);
        if (more) {
            const int k0 = (c + 1) * CHUNK + kg * 16;
#pragma unroll
            for (int i = 0; i < 16; ++i) {
                const int s = k0 + i;
                stage[i] = (s < n) ? x[(size_t)s * (BATCH * FEAT) + xoff] : 0.f;
            }
        }
        // MFMA on buf cur: 4 k-slices of 16 (loads above drain under this)
#pragma unroll
        for (int ks = 0; ks < 4; ++ks) {
            const int kloc = ks * 16 + 4 * lg;
            f16x4 a[4], bb[4];
#pragma unroll
            for (int r = 0; r < 4; ++r)
                a[r] = *(const f16x4*)&T[cur][(wm * 4 + r) * 16 + l15][kloc];
#pragma unroll
            for (int c2 = 0; c2 < 4; ++c2)
                bb[c2] = *(const f16x4*)&T[cur][(wn * 4 + c2) * 16 + l15][kloc];
#pragma unroll
            for (int r = 0; r < 4; ++r)
#pragma unroll
                for (int c2 = 0; c2 < 4; ++c2)
                    acc[r][c2] = __builtin_amdgcn_mfma_f32_16x16x16f16(
                        a[r], bb[c2], acc[r][c2], 0, 0, 0);
        }
        if (more) {
            const int nxt = cur ^ 1;
            const int kb = kg * 16;
#pragma unroll
            for (int i = 0; i < 16; i += 2) {
                _Float16 h0 = (_Float16)stage[i], h1 = (_Float16)stage[i + 1];
                float r0 = (float)h0, r1 = (float)h1;
                psum += r0 + r1;
                psq = fmaf(r0, r0, psq);
                psq = fmaf(r1, r1, psq);
                *(f16x2*)&T[nxt][f][kb + i] = (f16x2){h0, h1};
            }
            __syncthreads();   // uniform condition: block-wide
        }
    }

    // fold per-feature partials (4 kg-threads per feature)
    __syncthreads();
    red[0][kg][f] = psum;
    red[1][kg][f] = psq;
    __syncthreads();
    if (t < FEAT) {
        float s = red[0][0][t] + red[0][1][t] + red[0][2][t] + red[0][3][t];
        float q = red[1][0][t] + red[1][1][t] + red[1][2][t] + red[1][3][t];
        float m = s / (float)n;
        float var = (q - (float)n * m * m) / (float)(n - 1);
        ms[t] = m;
        is_[t] = (var > 0.f) ? rsqrtf(var) : 0.f;
    }
    __syncthreads();

    const float fn = (float)n;
    const float inv_nm1 = 1.f / (float)(n - 1);
#pragma unroll
    for (int c = 0; c < 4; ++c) {
        const int gj = (wn * 4 + c) * 16 + l15;
        const float mj = ms[gj], ij = is_[gj];
        int cnt = 0;
#pragma unroll
        for (int r = 0; r < 4; ++r) {
            const int gib = (wm * 4 + r) * 16 + 4 * lg;
#pragma unroll
            for (int q = 0; q < 4; ++q) {
                const int gi = gib + q;
                float cv = (acc[r][c][q] - fn * ms[gi] * mj) * inv_nm1 * is_[gi] * ij;
                if (gi <= gj && cv > 0.999f) cnt++;
            }
        }
        if (cnt) atomicAdd(&colsum[b * FEAT + gj], cnt);
    }
}

// stable order (selected features first) + counts, ballot prefix.
__global__ void k_select(const int* __restrict__ colsum, int* __restrict__ order,
                         int* __restrict__ counts) {
    __shared__ int wsum[4];
    const int b = blockIdx.x;
    const int j = threadIdx.x;         // 0..255
    const int sel = (colsum[b * FEAT + j] == 1) ? 1 : 0;
    unsigned long long mask = __ballot(sel);
    const int lane = j & 63;
    const int wid = j >> 6;
    int pre = __popcll(mask & ((1ull << lane) - 1ull));
    if (lane == 0) wsum[wid] = __popcll(mask);
    __syncthreads();
    int woff = 0;
#pragma unroll
    for (int w = 0; w < 4; ++w) woff += (w < wid) ? wsum[w] : 0;
    const int total = wsum[0] + wsum[1] + wsum[2] + wsum[3];
    if (sel) {
        order[b * FEAT + woff + pre] = j;
    } else {
        int unsel_pre = j - (woff + pre);
        order[b * FEAT + total + unsel_pre] = j;
    }
    if (j == 0) counts[b] = total;
}

// gather through LDS: stage GROWS rows coalesced (float4), permute in LDS,
// store contiguous dwords.
__global__ __launch_bounds__(256) void k_gather(
        const float* __restrict__ x, const int* __restrict__ order,
        const int* __restrict__ counts, float* __restrict__ out) {
    const int b = blockIdx.y;
    const int s0 = blockIdx.x * GROWS;
    const int t = threadIdx.x;

    __shared__ float T[GROWS][FEAT];
    __shared__ int ord_s[FEAT];
    __shared__ int cnt_s;

    ord_s[t] = order[b * FEAT + t];
    if (t == 0) cnt_s = counts[b];

    const size_t bbase = (size_t)b * FEAT;
#pragma unroll
    for (int i = 0; i < (GROWS * FEAT) / (256 * 4); ++i) {  // 4 float4/thread
        const int idx = i * 256 + t;
        const int row = idx >> 6;
        const int f4 = (idx & 63) * 4;
        float4 v = *(const float4*)&x[(size_t)(s0 + row) * (BATCH * FEAT) + bbase + f4];
        *(float4*)&T[row][f4] = v;
    }
    __syncthreads();

    const int o = ord_s[t];
    const bool keep = t < cnt_s;
#pragma unroll
    for (int r = 0; r < GROWS; ++r) {
        float v = T[r][o];
        out[(size_t)(s0 + r) * (BATCH * FEAT) + bbase + t] = keep ? v : 0.f;
    }
}

extern "C" void kernel_launch(void* const* d_in, const int* in_sizes, int n_in,
                              void* d_out, int out_size, void* d_ws, size_t ws_size,
                              hipStream_t stream) {
    const float* x = (const float*)d_in[0];
    const int* sep = (const int*)d_in[1];
    float* out = (float*)d_out;

    int* colsum = (int*)d_ws;
    int* order = colsum + BATCH * FEAT;
    int* counts = order + BATCH * FEAT;

    hipMemsetAsync(colsum, 0, BATCH * FEAT * sizeof(int), stream);

    k_cov<<<dim3(BATCH), dim3(1024), 0, stream>>>(x, sep, colsum);

    k_select<<<dim3(BATCH), dim3(FEAT), 0, stream>>>(colsum, order, counts);

    k_gather<<<dim3(S_TOT / GROWS, BATCH), dim3(256), 0, stream>>>(x, order, counts, out);
}

// Round 6
// 158.925 us; speedup vs baseline: 5.3577x; 1.0633x over previous
//
#include <hip/hip_runtime.h>

#define S_TOT 2048
#define BATCH 128
#define FEAT  256
#define CHUNK 64    // k-rows per pipeline stage
#define ROWH  68    // 64 halves + 4 pad; 136 B row stride
#define GROWS 16    // rows per gather block

typedef _Float16 f16x4 __attribute__((ext_vector_type(4)));
typedef _Float16 f16x2 __attribute__((ext_vector_type(2)));
typedef float f32x4 __attribute__((ext_vector_type(4)));

// Fused stats + Gram via MFMA, double-buffered, row-split 2 blocks/batch so
// all 256 CUs are used (R4 profile: 1 block/batch left half the chip idle).
// Correlation is affine-invariant: stage RAW f16 values, MFMA the Gram G,
// accumulate per-feature sum/sumsq of the SAME f16-rounded values in fp32,
// threshold (G - n*mi*mj) / ((n-1)*si*sj) > 0.999.
// Ref's +1e-6 std shift scales cov by ~2e-6: irrelevant vs 1e-3 margins.
// sigma=0 features: is_=0 -> cv=0 -> never selected (matches ref).
__global__ __launch_bounds__(1024) void k_cov(
        const float* __restrict__ x, const int* __restrict__ sep,
        int* __restrict__ colsum) {
    const int half = blockIdx.x;        // 0/1: which 128 Gram rows
    const int b = blockIdx.y;
    const int n = sep[0];
    const int t = threadIdx.x;
    const int l = t & 63;
    const int w = t >> 6;               // 0..15; wave tile = 32 rows x 64 cols
    const int wm = w >> 2, wn = w & 3;
    const int l15 = l & 15, lg = l >> 4;

    __shared__ _Float16 T[2][FEAT][ROWH];
    __shared__ float ms[FEAT], is_[FEAT];
    __shared__ int scount[FEAT];
    float* redf = (float*)&T[0][0][0];  // post-loop reuse: red[2][4][FEAT]

    // staging role: thread covers feature f, k-slots kg*16 .. kg*16+15
    const int f = t & 255;
    const int kg = t >> 8;              // 0..3

    f32x4 acc[2][4];
#pragma unroll
    for (int r = 0; r < 2; ++r)
#pragma unroll
        for (int c = 0; c < 4; ++c)
            acc[r][c] = (f32x4){0.f, 0.f, 0.f, 0.f};

    float psum = 0.f, psq = 0.f;
    float stage[16];

    const size_t xoff = (size_t)b * FEAT + f;
    const int NC = (n + CHUNK - 1) / CHUNK;

    if (t < FEAT) scount[t] = 0;

    // prologue: chunk 0 -> regs -> buf 0
    {
        const int k0 = kg * 16;
#pragma unroll
        for (int i = 0; i < 16; ++i) {
            const int s = k0 + i;
            stage[i] = (s < n) ? x[(size_t)s * (BATCH * FEAT) + xoff] : 0.f;
        }
#pragma unroll
        for (int i = 0; i < 16; i += 2) {
            _Float16 h0 = (_Float16)stage[i], h1 = (_Float16)stage[i + 1];
            float r0 = (float)h0, r1 = (float)h1;
            psum += r0 + r1;
            psq = fmaf(r0, r0, psq);
            psq = fmaf(r1, r1, psq);
            *(f16x2*)&T[0][f][k0 + i] = (f16x2){h0, h1};
        }
    }
    __syncthreads();

    for (int c = 0; c < NC; ++c) {
        const int cur = c & 1;
        const bool more = (c + 1 < NC);
        if (more) {
            const int k0 = (c + 1) * CHUNK + kg * 16;
#pragma unroll
            for (int i = 0; i < 16; ++i) {
                const int s = k0 + i;
                stage[i] = (s < n) ? x[(size_t)s * (BATCH * FEAT) + xoff] : 0.f;
            }
        }
        // MFMA on buf cur (prefetch loads drain under this)
#pragma unroll
        for (int ks = 0; ks < 4; ++ks) {
            const int kloc = ks * 16 + 4 * lg;
            f16x4 a[2], bb[4];
#pragma unroll
            for (int r = 0; r < 2; ++r)
                a[r] = *(const f16x4*)&T[cur][half * 128 + wm * 32 + r * 16 + l15][kloc];
#pragma unroll
            for (int c2 = 0; c2 < 4; ++c2)
                bb[c2] = *(const f16x4*)&T[cur][wn * 64 + c2 * 16 + l15][kloc];
#pragma unroll
            for (int r = 0; r < 2; ++r)
#pragma unroll
                for (int c2 = 0; c2 < 4; ++c2)
                    acc[r][c2] = __builtin_amdgcn_mfma_f32_16x16x16f16(
                        a[r], bb[c2], acc[r][c2], 0, 0, 0);
        }
        if (more) {
            const int nxt = cur ^ 1;
            const int kb = kg * 16;
#pragma unroll
            for (int i = 0; i < 16; i += 2) {
                _Float16 h0 = (_Float16)stage[i], h1 = (_Float16)stage[i + 1];
                float r0 = (float)h0, r1 = (float)h1;
                psum += r0 + r1;
                psq = fmaf(r0, r0, psq);
                psq = fmaf(r1, r1, psq);
                *(f16x2*)&T[nxt][f][kb + i] = (f16x2){h0, h1};
            }
            __syncthreads();
        }
    }

    // fold per-feature partials (4 kg-threads/feature); redf overlays T[0]
    __syncthreads();
    redf[kg * FEAT + f] = psum;
    redf[(4 + kg) * FEAT + f] = psq;
    __syncthreads();
    if (t < FEAT) {
        float s = redf[0 * FEAT + t] + redf[1 * FEAT + t] + redf[2 * FEAT + t] + redf[3 * FEAT + t];
        float q = redf[4 * FEAT + t] + redf[5 * FEAT + t] + redf[6 * FEAT + t] + redf[7 * FEAT + t];
        float m = s / (float)n;
        float var = (q - (float)n * m * m) / (float)(n - 1);
        ms[t] = m;
        is_[t] = (var > 0.f) ? rsqrtf(var) : 0.f;
    }
    __syncthreads();

    const float fn = (float)n;
    const float inv_nm1 = 1.f / (float)(n - 1);
#pragma unroll
    for (int c = 0; c < 4; ++c) {
        const int gj = wn * 64 + c * 16 + l15;
        const float mj = ms[gj], ij = is_[gj];
        int cnt = 0;
#pragma unroll
        for (int r = 0; r < 2; ++r) {
            const int gib = half * 128 + wm * 32 + r * 16 + 4 * lg;
#pragma unroll
            for (int q = 0; q < 4; ++q) {
                const int gi = gib + q;
                float cv = (acc[r][c][q] - fn * ms[gi] * mj) * inv_nm1 * is_[gi] * ij;
                if (gi <= gj && cv > 0.999f) cnt++;
            }
        }
        if (cnt) atomicAdd(&scount[gj], cnt);
    }
    __syncthreads();
    if (t < FEAT && scount[t]) atomicAdd(&colsum[b * FEAT + t], scount[t]);
}

// stable order (selected features first) + counts, ballot prefix.
__global__ void k_select(const int* __restrict__ colsum, int* __restrict__ order,
                         int* __restrict__ counts) {
    __shared__ int wsum[4];
    const int b = blockIdx.x;
    const int j = threadIdx.x;         // 0..255
    const int sel = (colsum[b * FEAT + j] == 1) ? 1 : 0;
    unsigned long long mask = __ballot(sel);
    const int lane = j & 63;
    const int wid = j >> 6;
    int pre = __popcll(mask & ((1ull << lane) - 1ull));
    if (lane == 0) wsum[wid] = __popcll(mask);
    __syncthreads();
    int woff = 0;
#pragma unroll
    for (int w = 0; w < 4; ++w) woff += (w < wid) ? wsum[w] : 0;
    const int total = wsum[0] + wsum[1] + wsum[2] + wsum[3];
    if (sel) {
        order[b * FEAT + woff + pre] = j;
    } else {
        int unsel_pre = j - (woff + pre);
        order[b * FEAT + total + unsel_pre] = j;
    }
    if (j == 0) counts[b] = total;
}

// gather through LDS: stage GROWS rows coalesced (float4), permute in LDS,
// store contiguous float4 (4 cols/thread).
__global__ __launch_bounds__(256) void k_gather(
        const float* __restrict__ x, const int* __restrict__ order,
        const int* __restrict__ counts, float* __restrict__ out) {
    const int b = blockIdx.y;
    const int s0 = blockIdx.x * GROWS;
    const int t = threadIdx.x;

    __shared__ float T[GROWS][FEAT];
    __shared__ int ord_s[FEAT];
    __shared__ int cnt_s;

    ord_s[t] = order[b * FEAT + t];
    if (t == 0) cnt_s = counts[b];

    const size_t bbase = (size_t)b * FEAT;
#pragma unroll
    for (int i = 0; i < (GROWS * FEAT) / (256 * 4); ++i) {  // 4 float4/thread
        const int idx = i * 256 + t;
        const int row = idx >> 6;
        const int f4 = (idx & 63) * 4;
        float4 v = *(const float4*)&x[(size_t)(s0 + row) * (BATCH * FEAT) + bbase + f4];
        *(float4*)&T[row][f4] = v;
    }
    __syncthreads();

    const int c4 = (t & 63) * 4;
    const int tr = t >> 6;               // 0..3
    const int cnt = cnt_s;
    const int o0 = ord_s[c4 + 0], o1 = ord_s[c4 + 1];
    const int o2 = ord_s[c4 + 2], o3 = ord_s[c4 + 3];
#pragma unroll
    for (int r = tr; r < GROWS; r += 4) {
        float4 v;
        v.x = (c4 + 0 < cnt) ? T[r][o0] : 0.f;
        v.y = (c4 + 1 < cnt) ? T[r][o1] : 0.f;
        v.z = (c4 + 2 < cnt) ? T[r][o2] : 0.f;
        v.w = (c4 + 3 < cnt) ? T[r][o3] : 0.f;
        *(float4*)&out[(size_t)(s0 + r) * (BATCH * FEAT) + bbase + c4] = v;
    }
}

extern "C" void kernel_launch(void* const* d_in, const int* in_sizes, int n_in,
                              void* d_out, int out_size, void* d_ws, size_t ws_size,
                              hipStream_t stream) {
    const float* x = (const float*)d_in[0];
    const int* sep = (const int*)d_in[1];
    float* out = (float*)d_out;

    int* colsum = (int*)d_ws;
    int* order = colsum + BATCH * FEAT;
    int* counts = order + BATCH * FEAT;

    hipMemsetAsync(colsum, 0, BATCH * FEAT * sizeof(int), stream);

    k_cov<<<dim3(2, BATCH), dim3(1024), 0, stream>>>(x, sep, colsum);

    k_select<<<dim3(BATCH), dim3(FEAT), 0, stream>>>(colsum, order, counts);

    k_gather<<<dim3(S_TOT / GROWS, BATCH), dim3(256), 0, stream>>>(x, order, counts, out);
}

// Round 7
// 157.203 us; speedup vs baseline: 5.4164x; 1.0110x over previous
//
#include <hip/hip_runtime.h>

#define S_TOT 2048
#define BATCH 128
#define FEAT  256
#define CHUNK 64    // k-rows per pipeline stage
#define ROWH  68    // 64 halves + 4 pad; 136 B row stride
#define GROWS 16    // rows per gather block

typedef _Float16 f16x4 __attribute__((ext_vector_type(4)));
typedef _Float16 f16x2 __attribute__((ext_vector_type(2)));
typedef float f32x4 __attribute__((ext_vector_type(4)));

// Fused stats + Gram via MFMA, double-buffered, row-split 2 blocks/batch so
// all 256 CUs are used (R4 profile: 1 block/batch left half the chip idle).
// Correlation is affine-invariant: stage RAW f16 values, MFMA the Gram G,
// accumulate per-feature sum/sumsq of the SAME f16-rounded values in fp32,
// threshold (G - n*mi*mj) / ((n-1)*si*sj) > 0.999.
// Ref's +1e-6 std shift scales cov by ~2e-6: irrelevant vs 1e-3 margins.
// sigma=0 features: is_=0 -> cv=0 -> never selected (matches ref).
__global__ __launch_bounds__(1024) void k_cov(
        const float* __restrict__ x, const int* __restrict__ sep,
        int* __restrict__ colsum) {
    const int half = blockIdx.x;        // 0/1: which 128 Gram rows
    const int b = blockIdx.y;
    const int n = sep[0];
    const int t = threadIdx.x;
    const int l = t & 63;
    const int w = t >> 6;               // 0..15; wave tile = 32 rows x 64 cols
    const int wm = w >> 2, wn = w & 3;
    const int l15 = l & 15, lg = l >> 4;

    __shared__ _Float16 T[2][FEAT][ROWH];
    __shared__ float ms[FEAT], is_[FEAT];
    __shared__ int scount[FEAT];
    float* redf = (float*)&T[0][0][0];  // post-loop reuse: red[2][4][FEAT]

    // staging role: thread covers feature f, k-slots kg*16 .. kg*16+15
    const int f = t & 255;
    const int kg = t >> 8;              // 0..3

    f32x4 acc[2][4];
#pragma unroll
    for (int r = 0; r < 2; ++r)
#pragma unroll
        for (int c = 0; c < 4; ++c)
            acc[r][c] = (f32x4){0.f, 0.f, 0.f, 0.f};

    float psum = 0.f, psq = 0.f;
    float stage[16];

    const size_t xoff = (size_t)b * FEAT + f;
    const int NC = (n + CHUNK - 1) / CHUNK;

    if (t < FEAT) scount[t] = 0;

    // prologue: chunk 0 -> regs -> buf 0
    {
        const int k0 = kg * 16;
#pragma unroll
        for (int i = 0; i < 16; ++i) {
            const int s = k0 + i;
            stage[i] = (s < n) ? x[(size_t)s * (BATCH * FEAT) + xoff] : 0.f;
        }
#pragma unroll
        for (int i = 0; i < 16; i += 2) {
            _Float16 h0 = (_Float16)stage[i], h1 = (_Float16)stage[i + 1];
            float r0 = (float)h0, r1 = (float)h1;
            psum += r0 + r1;
            psq = fmaf(r0, r0, psq);
            psq = fmaf(r1, r1, psq);
            *(f16x2*)&T[0][f][k0 + i] = (f16x2){h0, h1};
        }
    }
    __syncthreads();

    for (int c = 0; c < NC; ++c) {
        const int cur = c & 1;
        const bool more = (c + 1 < NC);
        if (more) {
            const int k0 = (c + 1) * CHUNK + kg * 16;
#pragma unroll
            for (int i = 0; i < 16; ++i) {
                const int s = k0 + i;
                stage[i] = (s < n) ? x[(size_t)s * (BATCH * FEAT) + xoff] : 0.f;
            }
        }
        // MFMA on buf cur (prefetch loads drain under this)
#pragma unroll
        for (int ks = 0; ks < 4; ++ks) {
            const int kloc = ks * 16 + 4 * lg;
            f16x4 a[2], bb[4];
#pragma unroll
            for (int r = 0; r < 2; ++r)
                a[r] = *(const f16x4*)&T[cur][half * 128 + wm * 32 + r * 16 + l15][kloc];
#pragma unroll
            for (int c2 = 0; c2 < 4; ++c2)
                bb[c2] = *(const f16x4*)&T[cur][wn * 64 + c2 * 16 + l15][kloc];
#pragma unroll
            for (int r = 0; r < 2; ++r)
#pragma unroll
                for (int c2 = 0; c2 < 4; ++c2)
                    acc[r][c2] = __builtin_amdgcn_mfma_f32_16x16x16f16(
                        a[r], bb[c2], acc[r][c2], 0, 0, 0);
        }
        if (more) {
            const int nxt = cur ^ 1;
            const int kb = kg * 16;
#pragma unroll
            for (int i = 0; i < 16; i += 2) {
                _Float16 h0 = (_Float16)stage[i], h1 = (_Float16)stage[i + 1];
                float r0 = (float)h0, r1 = (float)h1;
                psum += r0 + r1;
                psq = fmaf(r0, r0, psq);
                psq = fmaf(r1, r1, psq);
                *(f16x2*)&T[nxt][f][kb + i] = (f16x2){h0, h1};
            }
            __syncthreads();
        }
    }

    // fold per-feature partials (4 kg-threads/feature); redf overlays T[0]
    __syncthreads();
    redf[kg * FEAT + f] = psum;
    redf[(4 + kg) * FEAT + f] = psq;
    __syncthreads();
    if (t < FEAT) {
        float s = redf[0 * FEAT + t] + redf[1 * FEAT + t] + redf[2 * FEAT + t] + redf[3 * FEAT + t];
        float q = redf[4 * FEAT + t] + redf[5 * FEAT + t] + redf[6 * FEAT + t] + redf[7 * FEAT + t];
        float m = s / (float)n;
        float var = (q - (float)n * m * m) / (float)(n - 1);
        ms[t] = m;
        is_[t] = (var > 0.f) ? rsqrtf(var) : 0.f;
    }
    __syncthreads();

    const float fn = (float)n;
    const float inv_nm1 = 1.f / (float)(n - 1);
#pragma unroll
    for (int c = 0; c < 4; ++c) {
        const int gj = wn * 64 + c * 16 + l15;
        const float mj = ms[gj], ij = is_[gj];
        int cnt = 0;
#pragma unroll
        for (int r = 0; r < 2; ++r) {
            const int gib = half * 128 + wm * 32 + r * 16 + 4 * lg;
#pragma unroll
            for (int q = 0; q < 4; ++q) {
                const int gi = gib + q;
                float cv = (acc[r][c][q] - fn * ms[gi] * mj) * inv_nm1 * is_[gi] * ij;
                if (gi <= gj && cv > 0.999f) cnt++;
            }
        }
        if (cnt) atomicAdd(&scount[gj], cnt);
    }
    __syncthreads();
    if (t < FEAT && scount[t]) atomicAdd(&colsum[b * FEAT + t], scount[t]);
}

// stable order (selected features first) + counts, ballot prefix.
__global__ void k_select(const int* __restrict__ colsum, int* __restrict__ order,
                         int* __restrict__ counts) {
    __shared__ int wsum[4];
    const int b = blockIdx.x;
    const int j = threadIdx.x;         // 0..255
    const int sel = (colsum[b * FEAT + j] == 1) ? 1 : 0;
    unsigned long long mask = __ballot(sel);
    const int lane = j & 63;
    const int wid = j >> 6;
    int pre = __popcll(mask & ((1ull << lane) - 1ull));
    if (lane == 0) wsum[wid] = __popcll(mask);
    __syncthreads();
    int woff = 0;
#pragma unroll
    for (int w = 0; w < 4; ++w) woff += (w < wid) ? wsum[w] : 0;
    const int total = wsum[0] + wsum[1] + wsum[2] + wsum[3];
    if (sel) {
        order[b * FEAT + woff + pre] = j;
    } else {
        int unsel_pre = j - (woff + pre);
        order[b * FEAT + total + unsel_pre] = j;
    }
    if (j == 0) counts[b] = total;
}

// gather through LDS: stage GROWS rows coalesced (float4), permute in LDS,
// store contiguous float4 (4 cols/thread).
__global__ __launch_bounds__(256) void k_gather(
        const float* __restrict__ x, const int* __restrict__ order,
        const int* __restrict__ counts, float* __restrict__ out) {
    const int b = blockIdx.y;
    const int s0 = blockIdx.x * GROWS;
    const int t = threadIdx.x;

    __shared__ float T[GROWS][FEAT];
    __shared__ int ord_s[FEAT];
    __shared__ int cnt_s;

    ord_s[t] = order[b * FEAT + t];
    if (t == 0) cnt_s = counts[b];

    const size_t bbase = (size_t)b * FEAT;
#pragma unroll
    for (int i = 0; i < (GROWS * FEAT) / (256 * 4); ++i) {  // 4 float4/thread
        const int idx = i * 256 + t;
        const int row = idx >> 6;
        const int f4 = (idx & 63) * 4;
        float4 v = *(const float4*)&x[(size_t)(s0 + row) * (BATCH * FEAT) + bbase + f4];
        *(float4*)&T[row][f4] = v;
    }
    __syncthreads();

    const int c4 = (t & 63) * 4;
    const int tr = t >> 6;               // 0..3
    const int cnt = cnt_s;
    const int o0 = ord_s[c4 + 0], o1 = ord_s[c4 + 1];
    const int o2 = ord_s[c4 + 2], o3 = ord_s[c4 + 3];
#pragma unroll
    for (int r = tr; r < GROWS; r += 4) {
        float4 v;
        v.x = (c4 + 0 < cnt) ? T[r][o0] : 0.f;
        v.y = (c4 + 1 < cnt) ? T[r][o1] : 0.f;
        v.z = (c4 + 2 < cnt) ? T[r][o2] : 0.f;
        v.w = (c4 + 3 < cnt) ? T[r][o3] : 0.f;
        *(float4*)&out[(size_t)(s0 + r) * (BATCH * FEAT) + bbase + c4] = v;
    }
}

extern "C" void kernel_launch(void* const* d_in, const int* in_sizes, int n_in,
                              void* d_out, int out_size, void* d_ws, size_t ws_size,
                              hipStream_t stream) {
    const float* x = (const float*)d_in[0];
    const int* sep = (const int*)d_in[1];
    float* out = (float*)d_out;

    int* colsum = (int*)d_ws;
    int* order = colsum + BATCH * FEAT;
    int* counts = order + BATCH * FEAT;

    hipMemsetAsync(colsum, 0, BATCH * FEAT * sizeof(int), stream);

    k_cov<<<dim3(2, BATCH), dim3(1024), 0, stream>>>(x, sep, colsum);

    k_select<<<dim3(BATCH), dim3(FEAT), 0, stream>>>(colsum, order, counts);

    k_gather<<<dim3(S_TOT / GROWS, BATCH), dim3(256), 0, stream>>>(x, order, counts, out);
}

// Round 8
// 156.131 us; speedup vs baseline: 5.4535x; 1.0069x over previous
//
#include <hip/hip_runtime.h>

#define S_TOT 2048
#define BATCH 128
#define FEAT  256
#define CHUNK 64    // k-rows per pipeline stage
#define ROWH  68    // 64 halves + 4 pad; 136 B row stride
#define GROWS 16    // rows per gather block

typedef _Float16 f16x4 __attribute__((ext_vector_type(4)));
typedef _Float16 f16x2 __attribute__((ext_vector_type(2)));
typedef float f32x4 __attribute__((ext_vector_type(4)));

// Fused stats + Gram via MFMA, double-buffered, row-split 2 blocks/batch so
// all 256 CUs are used (R4 profile: 1 block/batch left half the chip idle).
// Correlation is affine-invariant: stage RAW f16 values, MFMA the Gram G,
// accumulate per-feature sum/sumsq of the SAME f16-rounded values in fp32,
// threshold (G - n*mi*mj) / ((n-1)*si*sj) > 0.999.
// Ref's +1e-6 std shift scales cov by ~2e-6: irrelevant vs 1e-3 margins.
// sigma=0 features: is_=0 -> cv=0 -> never selected (matches ref).
__global__ __launch_bounds__(1024) void k_cov(
        const float* __restrict__ x, const int* __restrict__ sep,
        int* __restrict__ colsum) {
    const int half = blockIdx.x;        // 0/1: which 128 Gram rows
    const int b = blockIdx.y;
    const int n = sep[0];
    const int t = threadIdx.x;
    const int l = t & 63;
    const int w = t >> 6;               // 0..15; wave tile = 32 rows x 64 cols
    const int wm = w >> 2, wn = w & 3;
    const int l15 = l & 15, lg = l >> 4;

    __shared__ _Float16 T[2][FEAT][ROWH];
    __shared__ float ms[FEAT], is_[FEAT];
    __shared__ int scount[FEAT];
    float* redf = (float*)&T[0][0][0];  // post-loop reuse: red[2][4][FEAT]

    // staging role: thread covers feature f, k-slots kg*16 .. kg*16+15
    const int f = t & 255;
    const int kg = t >> 8;              // 0..3

    f32x4 acc[2][4];
#pragma unroll
    for (int r = 0; r < 2; ++r)
#pragma unroll
        for (int c = 0; c < 4; ++c)
            acc[r][c] = (f32x4){0.f, 0.f, 0.f, 0.f};

    float psum = 0.f, psq = 0.f;
    float stage[16];

    const size_t xoff = (size_t)b * FEAT + f;
    const int NC = (n + CHUNK - 1) / CHUNK;

    if (t < FEAT) scount[t] = 0;

    // prologue: chunk 0 -> regs -> buf 0
    {
        const int k0 = kg * 16;
#pragma unroll
        for (int i = 0; i < 16; ++i) {
            const int s = k0 + i;
            stage[i] = (s < n) ? x[(size_t)s * (BATCH * FEAT) + xoff] : 0.f;
        }
#pragma unroll
        for (int i = 0; i < 16; i += 2) {
            _Float16 h0 = (_Float16)stage[i], h1 = (_Float16)stage[i + 1];
            float r0 = (float)h0, r1 = (float)h1;
            psum += r0 + r1;
            psq = fmaf(r0, r0, psq);
            psq = fmaf(r1, r1, psq);
            *(f16x2*)&T[0][f][k0 + i] = (f16x2){h0, h1};
        }
    }
    __syncthreads();

    for (int c = 0; c < NC; ++c) {
        const int cur = c & 1;
        const bool more = (c + 1 < NC);
        if (more) {
            const int k0 = (c + 1) * CHUNK + kg * 16;
#pragma unroll
            for (int i = 0; i < 16; ++i) {
                const int s = k0 + i;
                stage[i] = (s < n) ? x[(size_t)s * (BATCH * FEAT) + xoff] : 0.f;
            }
        }
        // MFMA on buf cur (prefetch loads drain under this)
#pragma unroll
        for (int ks = 0; ks < 4; ++ks) {
            const int kloc = ks * 16 + 4 * lg;
            f16x4 a[2], bb[4];
#pragma unroll
            for (int r = 0; r < 2; ++r)
                a[r] = *(const f16x4*)&T[cur][half * 128 + wm * 32 + r * 16 + l15][kloc];
#pragma unroll
            for (int c2 = 0; c2 < 4; ++c2)
                bb[c2] = *(const f16x4*)&T[cur][wn * 64 + c2 * 16 + l15][kloc];
#pragma unroll
            for (int r = 0; r < 2; ++r)
#pragma unroll
                for (int c2 = 0; c2 < 4; ++c2)
                    acc[r][c2] = __builtin_amdgcn_mfma_f32_16x16x16f16(
                        a[r], bb[c2], acc[r][c2], 0, 0, 0);
        }
        if (more) {
            const int nxt = cur ^ 1;
            const int kb = kg * 16;
#pragma unroll
            for (int i = 0; i < 16; i += 2) {
                _Float16 h0 = (_Float16)stage[i], h1 = (_Float16)stage[i + 1];
                float r0 = (float)h0, r1 = (float)h1;
                psum += r0 + r1;
                psq = fmaf(r0, r0, psq);
                psq = fmaf(r1, r1, psq);
                *(f16x2*)&T[nxt][f][kb + i] = (f16x2){h0, h1};
            }
            __syncthreads();
        }
    }

    // fold per-feature partials (4 kg-threads/feature); redf overlays T[0]
    __syncthreads();
    redf[kg * FEAT + f] = psum;
    redf[(4 + kg) * FEAT + f] = psq;
    __syncthreads();
    if (t < FEAT) {
        float s = redf[0 * FEAT + t] + redf[1 * FEAT + t] + redf[2 * FEAT + t] + redf[3 * FEAT + t];
        float q = redf[4 * FEAT + t] + redf[5 * FEAT + t] + redf[6 * FEAT + t] + redf[7 * FEAT + t];
        float m = s / (float)n;
        float var = (q - (float)n * m * m) / (float)(n - 1);
        ms[t] = m;
        is_[t] = (var > 0.f) ? rsqrtf(var) : 0.f;
    }
    __syncthreads();

    const float fn = (float)n;
    const float inv_nm1 = 1.f / (float)(n - 1);
#pragma unroll
    for (int c = 0; c < 4; ++c) {
        const int gj = wn * 64 + c * 16 + l15;
        const float mj = ms[gj], ij = is_[gj];
        int cnt = 0;
#pragma unroll
        for (int r = 0; r < 2; ++r) {
            const int gib = half * 128 + wm * 32 + r * 16 + 4 * lg;
#pragma unroll
            for (int q = 0; q < 4; ++q) {
                const int gi = gib + q;
                float cv = (acc[r][c][q] - fn * ms[gi] * mj) * inv_nm1 * is_[gi] * ij;
                if (gi <= gj && cv > 0.999f) cnt++;
            }
        }
        if (cnt) atomicAdd(&scount[gj], cnt);
    }
    __syncthreads();
    if (t < FEAT && scount[t]) atomicAdd(&colsum[b * FEAT + t], scount[t]);
}

// stable order (selected features first) + counts, ballot prefix.
__global__ void k_select(const int* __restrict__ colsum, int* __restrict__ order,
                         int* __restrict__ counts) {
    __shared__ int wsum[4];
    const int b = blockIdx.x;
    const int j = threadIdx.x;         // 0..255
    const int sel = (colsum[b * FEAT + j] == 1) ? 1 : 0;
    unsigned long long mask = __ballot(sel);
    const int lane = j & 63;
    const int wid = j >> 6;
    int pre = __popcll(mask & ((1ull << lane) - 1ull));
    if (lane == 0) wsum[wid] = __popcll(mask);
    __syncthreads();
    int woff = 0;
#pragma unroll
    for (int w = 0; w < 4; ++w) woff += (w < wid) ? wsum[w] : 0;
    const int total = wsum[0] + wsum[1] + wsum[2] + wsum[3];
    if (sel) {
        order[b * FEAT + woff + pre] = j;
    } else {
        int unsel_pre = j - (woff + pre);
        order[b * FEAT + total + unsel_pre] = j;
    }
    if (j == 0) counts[b] = total;
}

// gather through LDS: stage GROWS rows coalesced (float4), permute in LDS,
// store contiguous float4 (4 cols/thread).
__global__ __launch_bounds__(256) void k_gather(
        const float* __restrict__ x, const int* __restrict__ order,
        const int* __restrict__ counts, float* __restrict__ out) {
    const int b = blockIdx.y;
    const int s0 = blockIdx.x * GROWS;
    const int t = threadIdx.x;

    __shared__ float T[GROWS][FEAT];
    __shared__ int ord_s[FEAT];
    __shared__ int cnt_s;

    ord_s[t] = order[b * FEAT + t];
    if (t == 0) cnt_s = counts[b];

    const size_t bbase = (size_t)b * FEAT;
#pragma unroll
    for (int i = 0; i < (GROWS * FEAT) / (256 * 4); ++i) {  // 4 float4/thread
        const int idx = i * 256 + t;
        const int row = idx >> 6;
        const int f4 = (idx & 63) * 4;
        float4 v = *(const float4*)&x[(size_t)(s0 + row) * (BATCH * FEAT) + bbase + f4];
        *(float4*)&T[row][f4] = v;
    }
    __syncthreads();

    const int c4 = (t & 63) * 4;
    const int tr = t >> 6;               // 0..3
    const int cnt = cnt_s;
    const int o0 = ord_s[c4 + 0], o1 = ord_s[c4 + 1];
    const int o2 = ord_s[c4 + 2], o3 = ord_s[c4 + 3];
#pragma unroll
    for (int r = tr; r < GROWS; r += 4) {
        float4 v;
        v.x = (c4 + 0 < cnt) ? T[r][o0] : 0.f;
        v.y = (c4 + 1 < cnt) ? T[r][o1] : 0.f;
        v.z = (c4 + 2 < cnt) ? T[r][o2] : 0.f;
        v.w = (c4 + 3 < cnt) ? T[r][o3] : 0.f;
        *(float4*)&out[(size_t)(s0 + r) * (BATCH * FEAT) + bbase + c4] = v;
    }
}

extern "C" void kernel_launch(void* const* d_in, const int* in_sizes, int n_in,
                              void* d_out, int out_size, void* d_ws, size_t ws_size,
                              hipStream_t stream) {
    const float* x = (const float*)d_in[0];
    const int* sep = (const int*)d_in[1];
    float* out = (float*)d_out;

    int* colsum = (int*)d_ws;
    int* order = colsum + BATCH * FEAT;
    int* counts = order + BATCH * FEAT;

    hipMemsetAsync(colsum, 0, BATCH * FEAT * sizeof(int), stream);

    k_cov<<<dim3(2, BATCH), dim3(1024), 0, stream>>>(x, sep, colsum);

    k_select<<<dim3(BATCH), dim3(FEAT), 0, stream>>>(colsum, order, counts);

    k_gather<<<dim3(S_TOT / GROWS, BATCH), dim3(256), 0, stream>>>(x, order, counts, out);
}